// Round 2
// baseline (208.451 us; speedup 1.0000x reference)
//
#include <hip/hip_runtime.h>

#define N_NODES 100000
#define N_EDGES 3200000
#define D_FEAT  128
#define MAX_COPIES 64

// ---------------------------------------------------------------------------
// Kernel 1: per-node feature row-sum. 32 lanes per row, float4 per lane
// (16B/lane -> fully coalesced 512B per half-wave). Two rows per wave64;
// shfl_xor offsets < 32 stay within each 32-lane half.
// ---------------------------------------------------------------------------
__global__ void __launch_bounds__(256) rowsum_kernel(
    const float* __restrict__ feat,
    float* __restrict__ rowsum)
{
    const int gid = (int)(blockIdx.x * blockDim.x + threadIdx.x);
    const int row = gid >> 5;          // 32 threads per row
    const int sub = gid & 31;
    if (row >= N_NODES) return;

    const float4 v = reinterpret_cast<const float4*>(
        feat + (size_t)row * D_FEAT)[sub];
    float s = (v.x + v.y) + (v.z + v.w);

    #pragma unroll
    for (int off = 16; off > 0; off >>= 1)
        s += __shfl_xor(s, off, 64);

    if (sub == 0) rowsum[row] = s;
}

// ---------------------------------------------------------------------------
// Kernel 2: edge scatter-add into PER-WORKGROUP private copies with
// WORKGROUP-scope atomics. A workgroup is resident on one XCD, so these
// atomics execute (cached) in that XCD's TCC instead of memory-side ->
// no 32B EA transaction per atomic. Each block zero-inits its own copy
// first (ws is poisoned and never re-poisoned).
// ---------------------------------------------------------------------------
__global__ void __launch_bounds__(1024) scatter_kernel(
    const int* __restrict__ edge_src,
    const int* __restrict__ edge_dst,
    const float* __restrict__ rowsum,
    float* __restrict__ copies,
    int edges_per_block)
{
    float* __restrict__ myc = copies + (size_t)blockIdx.x * N_NODES;
    const int tid = (int)threadIdx.x;

    // zero my private copy (N_NODES divisible by 4)
    float4 z; z.x = z.y = z.z = z.w = 0.0f;
    for (int i = tid; i < N_NODES / 4; i += (int)blockDim.x)
        reinterpret_cast<float4*>(myc)[i] = z;
    __syncthreads();

    const int begin = (int)blockIdx.x * edges_per_block;
    int end = begin + edges_per_block;
    if (end > N_EDGES) end = N_EDGES;

    for (int e = begin + tid * 4; e < end; e += (int)blockDim.x * 4) {
        const int4 s4 = *reinterpret_cast<const int4*>(edge_src + e);
        const int4 d4 = *reinterpret_cast<const int4*>(edge_dst + e);

        const float v0 = rowsum[s4.x];
        const float v1 = rowsum[s4.y];
        const float v2 = rowsum[s4.z];
        const float v3 = rowsum[s4.w];

        __hip_atomic_fetch_add(&myc[d4.x], v0, __ATOMIC_RELAXED, __HIP_MEMORY_SCOPE_WORKGROUP);
        __hip_atomic_fetch_add(&myc[d4.y], v1, __ATOMIC_RELAXED, __HIP_MEMORY_SCOPE_WORKGROUP);
        __hip_atomic_fetch_add(&myc[d4.z], v2, __ATOMIC_RELAXED, __HIP_MEMORY_SCOPE_WORKGROUP);
        __hip_atomic_fetch_add(&myc[d4.w], v3, __ATOMIC_RELAXED, __HIP_MEMORY_SCOPE_WORKGROUP);
    }
}

// ---------------------------------------------------------------------------
// Kernel 3: reduce the private copies + activation chain + int cast, fused.
// float4 per thread; consecutive threads -> coalesced within each copy.
// ---------------------------------------------------------------------------
__global__ void __launch_bounds__(256) reduce_final_kernel(
    const float* __restrict__ copies,
    int ncopy,
    int* __restrict__ out)
{
    const int i4 = (int)(blockIdx.x * blockDim.x + threadIdx.x);
    if (i4 >= N_NODES / 4) return;

    float4 s; s.x = s.y = s.z = s.w = 0.0f;
    for (int c = 0; c < ncopy; ++c) {
        const float4 v = reinterpret_cast<const float4*>(
            copies + (size_t)c * N_NODES)[i4];
        s.x += v.x; s.y += v.y; s.z += v.z; s.w += v.w;
    }

    // out = int32( 10 * leaky( 16 * leaky(x, 0.1), 0.1) ), trunc toward zero
    auto act = [](float x) -> int {
        const float a1 = (x  > 0.0f) ? x  : 0.1f * x;
        const float r2 = 16.0f * a1;
        const float a2 = (r2 > 0.0f) ? r2 : 0.1f * r2;
        return (int)(10.0f * a2);
    };

    int4 o;
    o.x = act(s.x); o.y = act(s.y); o.z = act(s.z); o.w = act(s.w);
    reinterpret_cast<int4*>(out)[i4] = o;
}

extern "C" void kernel_launch(void* const* d_in, const int* in_sizes, int n_in,
                              void* d_out, int out_size, void* d_ws, size_t ws_size,
                              hipStream_t stream)
{
    const float* feat     = (const float*)d_in[0];
    const int*   edge_src = (const int*)d_in[1];
    const int*   edge_dst = (const int*)d_in[2];
    int*         out      = (int*)d_out;

    float* rowsum = (float*)d_ws;              // N_NODES floats
    float* copies = rowsum + N_NODES;          // ncopy x N_NODES floats

    // ncopy bounded by workspace size (deterministic: ws_size fixed per session)
    long long avail = (long long)(ws_size / 4) - N_NODES;
    int ncopy = (int)(avail / N_NODES);
    if (ncopy > MAX_COPIES) ncopy = MAX_COPIES;
    if (ncopy < 1) ncopy = 1;   // degenerate fallback: single block does all edges

    // Kernel 1: 32 threads per node
    {
        const int threads = 256;
        const long long total = (long long)N_NODES * 32;
        const int blocks = (int)((total + threads - 1) / threads);
        rowsum_kernel<<<blocks, threads, 0, stream>>>(feat, rowsum);
    }

    // Kernel 2: one block per private copy, workgroup-scope atomics
    {
        int epb = (N_EDGES + ncopy - 1) / ncopy;
        epb = (epb + 3) & ~3;                  // multiple of 4 for int4 loads
        scatter_kernel<<<ncopy, 1024, 0, stream>>>(edge_src, edge_dst, rowsum,
                                                   copies, epb);
    }

    // Kernel 3: fused reduce + activations + int cast
    {
        const int threads = 256;
        const int n_thr = N_NODES / 4;
        const int blocks = (n_thr + threads - 1) / threads;
        reduce_final_kernel<<<blocks, threads, 0, stream>>>(copies, ncopy, out);
    }
}

// Round 3
// 64.664 us; speedup vs baseline: 3.2236x; 3.2236x over previous
//
#include <hip/hip_runtime.h>

#define N_NODES 100000
#define N_EDGES 3200000
#define D_FEAT  128
#define SLICE   33344          // 3 slices cover 100000; 33344*4B = 130.25 KB LDS
#define SLICE4  (SLICE / 4)    // 8336
#define N_SLICES 3
#define MAX_B   85             // 3*85 = 255 blocks ~ one per CU

// ---------------------------------------------------------------------------
// Kernel 1: per-node feature row-sum. 32 lanes per row, float4 per lane.
// ---------------------------------------------------------------------------
__global__ void __launch_bounds__(256) rowsum_kernel(
    const float* __restrict__ feat,
    float* __restrict__ rowsum)
{
    const int gid = (int)(blockIdx.x * blockDim.x + threadIdx.x);
    const int row = gid >> 5;
    const int sub = gid & 31;
    if (row >= N_NODES) return;

    const float4 v = reinterpret_cast<const float4*>(
        feat + (size_t)row * D_FEAT)[sub];
    float s = (v.x + v.y) + (v.z + v.w);

    #pragma unroll
    for (int off = 16; off > 0; off >>= 1)
        s += __shfl_xor(s, off, 64);

    if (sub == 0) rowsum[row] = s;
}

// ---------------------------------------------------------------------------
// Kernel 2: LDS-privatized scatter. blockIdx.y = slice s, blockIdx.x = chunk b.
// Scan my edge chunk, filter dst into [lo, lo+len), ds_add_f32 into LDS,
// then flush LDS slice with coalesced float4 writes to copies[(s*B + b)].
// Edge indices are read coalesced (int4 = 4 edges/thread); rowsum gathers are
// random 4B reads over a 400 KB L2-resident table.
// ---------------------------------------------------------------------------
__global__ void __launch_bounds__(1024) scatter_kernel(
    const int* __restrict__ edge_src,
    const int* __restrict__ edge_dst,
    const float* __restrict__ rowsum,
    float* __restrict__ copies,
    int B, int edges_per_block)
{
    __shared__ float lds[SLICE];

    const int tid = (int)threadIdx.x;
    const int b   = (int)blockIdx.x;
    const int s   = (int)blockIdx.y;
    const int lo  = s * SLICE;
    const int len = (N_NODES - lo < SLICE) ? (N_NODES - lo) : SLICE;

    // zero my LDS slice
    float4 z; z.x = z.y = z.z = z.w = 0.0f;
    #pragma unroll 2
    for (int i = tid; i < SLICE4; i += 1024)
        reinterpret_cast<float4*>(lds)[i] = z;
    __syncthreads();

    const int begin = b * edges_per_block;
    int end = begin + edges_per_block;
    if (end > N_EDGES) end = N_EDGES;

    for (int e = begin + tid * 4; e < end; e += 1024 * 4) {
        const int4 d4 = *reinterpret_cast<const int4*>(edge_dst + e);
        const int4 s4 = *reinterpret_cast<const int4*>(edge_src + e);

        unsigned j0 = (unsigned)(d4.x - lo);
        unsigned j1 = (unsigned)(d4.y - lo);
        unsigned j2 = (unsigned)(d4.z - lo);
        unsigned j3 = (unsigned)(d4.w - lo);

        if (j0 < (unsigned)len) atomicAdd(&lds[j0], rowsum[s4.x]);
        if (j1 < (unsigned)len) atomicAdd(&lds[j1], rowsum[s4.y]);
        if (j2 < (unsigned)len) atomicAdd(&lds[j2], rowsum[s4.z]);
        if (j3 < (unsigned)len) atomicAdd(&lds[j3], rowsum[s4.w]);
    }
    __syncthreads();

    // flush: plain coalesced writes (no atomics touch HBM)
    float* __restrict__ dstp = copies + ((size_t)s * B + b) * SLICE;
    const int len4 = len >> 2;   // all slice lengths divisible by 4
    for (int i = tid; i < len4; i += 1024)
        reinterpret_cast<float4*>(dstp)[i] =
            reinterpret_cast<const float4*>(lds)[i];
}

// ---------------------------------------------------------------------------
// Kernel 3: reduce the B copies per slice + activation chain + int cast.
// One float4 (4 nodes) per thread; coalesced within each copy.
// ---------------------------------------------------------------------------
__global__ void __launch_bounds__(256) reduce_final_kernel(
    const float* __restrict__ copies,
    int B,
    int* __restrict__ out)
{
    const int i4 = (int)(blockIdx.x * blockDim.x + threadIdx.x);
    if (i4 >= N_NODES / 4) return;

    const int s  = (i4 >= 2 * SLICE4) ? 2 : (i4 >= SLICE4 ? 1 : 0);
    const int j4 = i4 - s * SLICE4;

    float4 acc; acc.x = acc.y = acc.z = acc.w = 0.0f;
    const float4* base = reinterpret_cast<const float4*>(copies)
                       + (size_t)s * B * SLICE4 + j4;
    for (int c = 0; c < B; ++c) {
        const float4 v = base[(size_t)c * SLICE4];
        acc.x += v.x; acc.y += v.y; acc.z += v.z; acc.w += v.w;
    }

    auto act = [](float x) -> int {
        const float a1 = (x  > 0.0f) ? x  : 0.1f * x;
        const float r2 = 16.0f * a1;
        const float a2 = (r2 > 0.0f) ? r2 : 0.1f * r2;
        return (int)(10.0f * a2);
    };

    int4 o;
    o.x = act(acc.x); o.y = act(acc.y); o.z = act(acc.z); o.w = act(acc.w);
    reinterpret_cast<int4*>(out)[i4] = o;
}

extern "C" void kernel_launch(void* const* d_in, const int* in_sizes, int n_in,
                              void* d_out, int out_size, void* d_ws, size_t ws_size,
                              hipStream_t stream)
{
    const float* feat     = (const float*)d_in[0];
    const int*   edge_src = (const int*)d_in[1];
    const int*   edge_dst = (const int*)d_in[2];
    int*         out      = (int*)d_out;

    float* rowsum = (float*)d_ws;              // N_NODES floats
    float* copies = rowsum + N_NODES;          // 3*B*SLICE floats

    // size B (blocks per slice) from workspace; deterministic per session
    size_t avail = (ws_size / 4 > (size_t)N_NODES) ? ws_size / 4 - N_NODES : 0;
    int B = (int)(avail / ((size_t)N_SLICES * SLICE));
    if (B > MAX_B) B = MAX_B;
    if (B < 1) B = 1;

    int epb = (N_EDGES + B - 1) / B;
    epb = (epb + 3) & ~3;                      // multiple of 4 for int4 loads

    // Kernel 1: 32 threads per node
    {
        const int threads = 256;
        const long long total = (long long)N_NODES * 32;
        const int blocks = (int)((total + threads - 1) / threads);
        rowsum_kernel<<<blocks, threads, 0, stream>>>(feat, rowsum);
    }

    // Kernel 2: grid (B, 3) — LDS-privatized scatter
    {
        dim3 grid(B, N_SLICES);
        scatter_kernel<<<grid, 1024, 0, stream>>>(edge_src, edge_dst, rowsum,
                                                  copies, B, epb);
    }

    // Kernel 3: fused reduce + activations + int cast
    {
        const int threads = 256;
        const int blocks = (N_NODES / 4 + threads - 1) / threads;
        reduce_final_kernel<<<blocks, threads, 0, stream>>>(copies, B, out);
    }
}

// Round 4
// 52.942 us; speedup vs baseline: 3.9374x; 1.2214x over previous
//
#include <hip/hip_runtime.h>

#define N_NODES 100000
#define N_EDGES 3200000
#define D_FEAT  128
#define SLICE   33344          // 3 slices cover 100000; 33344*4B = 130.25 KB LDS
#define SLICE4  (SLICE / 4)    // 8336
#define N_SLICES 3
#define MAX_B   85             // 3*85 = 255 blocks ~ one per CU

// ---------------------------------------------------------------------------
// Kernel 1: per-node feature row-sum. 32 lanes per row, float4 per lane.
// ---------------------------------------------------------------------------
__global__ void __launch_bounds__(256) rowsum_kernel(
    const float* __restrict__ feat,
    float* __restrict__ rowsum)
{
    const int gid = (int)(blockIdx.x * blockDim.x + threadIdx.x);
    const int row = gid >> 5;
    const int sub = gid & 31;
    if (row >= N_NODES) return;

    const float4 v = reinterpret_cast<const float4*>(
        feat + (size_t)row * D_FEAT)[sub];
    float s = (v.x + v.y) + (v.z + v.w);

    #pragma unroll
    for (int off = 16; off > 0; off >>= 1)
        s += __shfl_xor(s, off, 64);

    if (sub == 0) rowsum[row] = s;
}

// ---------------------------------------------------------------------------
// Kernel 2: LDS-privatized scatter, 8 edges/thread/iter with index prefetch.
// blockIdx.y = slice, blockIdx.x = edge chunk. Filter dst into slice,
// ds_add_f32 into LDS, flush with coalesced float4 writes.
// ---------------------------------------------------------------------------
__global__ void __launch_bounds__(1024) scatter_kernel(
    const int* __restrict__ edge_src,
    const int* __restrict__ edge_dst,
    const float* __restrict__ rowsum,
    float* __restrict__ copies,
    int B, int edges_per_block)
{
    __shared__ float lds[SLICE];

    const int tid = (int)threadIdx.x;
    const int b   = (int)blockIdx.x;
    const int s   = (int)blockIdx.y;
    const int lo  = s * SLICE;
    const int len = (N_NODES - lo < SLICE) ? (N_NODES - lo) : SLICE;

    // zero my LDS slice
    float4 z; z.x = z.y = z.z = z.w = 0.0f;
    for (int i = tid; i < SLICE4; i += 1024)
        reinterpret_cast<float4*>(lds)[i] = z;
    __syncthreads();

    const int begin = b * edges_per_block;
    int end = begin + edges_per_block;
    if (end > N_EDGES) end = N_EDGES;

    const int STRIDE = 1024 * 8;
    int e = begin + tid * 8;

    // prime: load first 8 indices (two int4 per array)
    int4 d0, d1, s0, s1;
    bool v0 = (e < end), v1 = (e + 4 < end);
    if (v0) { d0 = *reinterpret_cast<const int4*>(edge_dst + e);
              s0 = *reinterpret_cast<const int4*>(edge_src + e); }
    if (v1) { d1 = *reinterpret_cast<const int4*>(edge_dst + e + 4);
              s1 = *reinterpret_cast<const int4*>(edge_src + e + 4); }

    while (v0) {
        // software-prefetch next iteration's indices
        const int en = e + STRIDE;
        int4 nd0, nd1, ns0, ns1;
        const bool nv0 = (en < end), nv1 = (en + 4 < end);
        if (nv0) { nd0 = *reinterpret_cast<const int4*>(edge_dst + en);
                   ns0 = *reinterpret_cast<const int4*>(edge_src + en); }
        if (nv1) { nd1 = *reinterpret_cast<const int4*>(edge_dst + en + 4);
                   ns1 = *reinterpret_cast<const int4*>(edge_src + en + 4); }

        // gather values (predicated on slice membership) — up to 8 in flight
        unsigned j0 = (unsigned)(d0.x - lo), j1 = (unsigned)(d0.y - lo);
        unsigned j2 = (unsigned)(d0.z - lo), j3 = (unsigned)(d0.w - lo);
        float w0 = (j0 < (unsigned)len) ? rowsum[s0.x] : 0.0f;
        float w1 = (j1 < (unsigned)len) ? rowsum[s0.y] : 0.0f;
        float w2 = (j2 < (unsigned)len) ? rowsum[s0.z] : 0.0f;
        float w3 = (j3 < (unsigned)len) ? rowsum[s0.w] : 0.0f;

        unsigned j4 = 0, j5 = 0, j6 = 0, j7 = 0;
        float w4 = 0.0f, w5 = 0.0f, w6 = 0.0f, w7 = 0.0f;
        if (v1) {
            j4 = (unsigned)(d1.x - lo); j5 = (unsigned)(d1.y - lo);
            j6 = (unsigned)(d1.z - lo); j7 = (unsigned)(d1.w - lo);
            w4 = (j4 < (unsigned)len) ? rowsum[s1.x] : 0.0f;
            w5 = (j5 < (unsigned)len) ? rowsum[s1.y] : 0.0f;
            w6 = (j6 < (unsigned)len) ? rowsum[s1.z] : 0.0f;
            w7 = (j7 < (unsigned)len) ? rowsum[s1.w] : 0.0f;
        }

        if (j0 < (unsigned)len) atomicAdd(&lds[j0], w0);
        if (j1 < (unsigned)len) atomicAdd(&lds[j1], w1);
        if (j2 < (unsigned)len) atomicAdd(&lds[j2], w2);
        if (j3 < (unsigned)len) atomicAdd(&lds[j3], w3);
        if (v1) {
            if (j4 < (unsigned)len) atomicAdd(&lds[j4], w4);
            if (j5 < (unsigned)len) atomicAdd(&lds[j5], w5);
            if (j6 < (unsigned)len) atomicAdd(&lds[j6], w6);
            if (j7 < (unsigned)len) atomicAdd(&lds[j7], w7);
        }

        e = en; v0 = nv0; v1 = nv1;
        d0 = nd0; d1 = nd1; s0 = ns0; s1 = ns1;
    }
    __syncthreads();

    // flush: plain coalesced writes (no atomics touch HBM)
    float* __restrict__ dstp = copies + ((size_t)s * B + b) * SLICE;
    const int len4 = len >> 2;   // all slice lengths divisible by 4
    for (int i = tid; i < len4; i += 1024)
        reinterpret_cast<float4*>(dstp)[i] =
            reinterpret_cast<const float4*>(lds)[i];
}

// ---------------------------------------------------------------------------
// Kernel 3: reduce the B copies per slice + activation chain + int cast.
// ---------------------------------------------------------------------------
__global__ void __launch_bounds__(256) reduce_final_kernel(
    const float* __restrict__ copies,
    int B,
    int* __restrict__ out)
{
    const int i4 = (int)(blockIdx.x * blockDim.x + threadIdx.x);
    if (i4 >= N_NODES / 4) return;

    const int s  = (i4 >= 2 * SLICE4) ? 2 : (i4 >= SLICE4 ? 1 : 0);
    const int j4 = i4 - s * SLICE4;

    float4 acc; acc.x = acc.y = acc.z = acc.w = 0.0f;
    const float4* base = reinterpret_cast<const float4*>(copies)
                       + (size_t)s * B * SLICE4 + j4;
    #pragma unroll 4
    for (int c = 0; c < B; ++c) {
        const float4 v = base[(size_t)c * SLICE4];
        acc.x += v.x; acc.y += v.y; acc.z += v.z; acc.w += v.w;
    }

    auto act = [](float x) -> int {
        const float a1 = (x  > 0.0f) ? x  : 0.1f * x;
        const float r2 = 16.0f * a1;
        const float a2 = (r2 > 0.0f) ? r2 : 0.1f * r2;
        return (int)(10.0f * a2);
    };

    int4 o;
    o.x = act(acc.x); o.y = act(acc.y); o.z = act(acc.z); o.w = act(acc.w);
    reinterpret_cast<int4*>(out)[i4] = o;
}

extern "C" void kernel_launch(void* const* d_in, const int* in_sizes, int n_in,
                              void* d_out, int out_size, void* d_ws, size_t ws_size,
                              hipStream_t stream)
{
    const float* feat     = (const float*)d_in[0];
    const int*   edge_src = (const int*)d_in[1];
    const int*   edge_dst = (const int*)d_in[2];
    int*         out      = (int*)d_out;

    float* rowsum = (float*)d_ws;              // N_NODES floats
    float* copies = rowsum + N_NODES;          // 3*B*SLICE floats

    size_t avail = (ws_size / 4 > (size_t)N_NODES) ? ws_size / 4 - N_NODES : 0;
    int B = (int)(avail / ((size_t)N_SLICES * SLICE));
    if (B > MAX_B) B = MAX_B;
    if (B < 1) B = 1;

    int epb = (N_EDGES + B - 1) / B;
    epb = (epb + 7) & ~7;                      // multiple of 8 for the unroll

    // Kernel 1: 32 threads per node
    {
        const int threads = 256;
        const long long total = (long long)N_NODES * 32;
        const int blocks = (int)((total + threads - 1) / threads);
        rowsum_kernel<<<blocks, threads, 0, stream>>>(feat, rowsum);
    }

    // Kernel 2: grid (B, 3) — LDS-privatized scatter
    {
        dim3 grid(B, N_SLICES);
        scatter_kernel<<<grid, 1024, 0, stream>>>(edge_src, edge_dst, rowsum,
                                                  copies, B, epb);
    }

    // Kernel 3: fused reduce + activations + int cast
    {
        const int threads = 256;
        const int blocks = (N_NODES / 4 + threads - 1) / threads;
        reduce_final_kernel<<<blocks, threads, 0, stream>>>(copies, B, out);
    }
}